// Round 5
// baseline (2235.878 us; speedup 1.0000x reference)
//
#include <hip/hip_runtime.h>

#define BT     32768
#define HIDDEN 512
#define DDIM   256
#define KCODE  1024
#define NQUANT 8

typedef _Float16 f16;
typedef _Float16 f16x8 __attribute__((ext_vector_type(8)));
typedef float f32x4 __attribute__((ext_vector_type(4)));
typedef float f32x8 __attribute__((ext_vector_type(8)));

#define LO_SCALE 64.0f
#define LO_INV   0.015625f

// ---------------------------------------------------------------------------
// cnorm: ||c||^2 for all NQ*K codes (fp32 exact)
// ---------------------------------------------------------------------------
__global__ __launch_bounds__(256) void cnorm_kernel(const float* __restrict__ cb,
                                                    float* __restrict__ cnorm) {
  __shared__ float red[256];
  const int code = blockIdx.x;
  const float v = cb[(size_t)code * DDIM + threadIdx.x];
  red[threadIdx.x] = v * v;
  __syncthreads();
  for (int s = 128; s > 0; s >>= 1) {
    if (threadIdx.x < s) red[threadIdx.x] += red[threadIdx.x + s];
    __syncthreads();
  }
  if (threadIdx.x == 0) cnorm[code] = red[0];
}

// ---------------------------------------------------------------------------
// codebooks -> f16 hi/lo ext: cbext[c][0..255]=hi, [256..511]=lo*64
// ---------------------------------------------------------------------------
__global__ __launch_bounds__(256) void cbext_conv(const float* __restrict__ cb,
                                                  f16* __restrict__ cbext) {
  const size_t idx = (size_t)blockIdx.x * 256 + threadIdx.x;
  const size_t c = idx >> 8;
  const int d = (int)(idx & 255);
  const float v = cb[idx];
  const f16 hi = (f16)v;
  cbext[c * 512 + d] = hi;
  cbext[c * 512 + 256 + d] = (f16)((v - (float)hi) * LO_SCALE);
}

// ---------------------------------------------------------------------------
// weight -> f16 hi/lo ext: Wext[n][0..K-1]=hi, [K..2K-1]=lo*64
// ---------------------------------------------------------------------------
__global__ __launch_bounds__(256) void bext_conv(const float* __restrict__ W,
                                                 f16* __restrict__ Wext,
                                                 int N, int K) {
  const int idx = blockIdx.x * 256 + threadIdx.x;
  if (idx >= N * K) return;
  const int n = idx / K, k = idx - n * K;
  const float v = W[idx];
  const f16 hi = (f16)v;
  Wext[(size_t)n * 2 * K + k] = hi;
  Wext[(size_t)n * 2 * K + K + k] = (f16)((v - (float)hi) * LO_SCALE);
}

__global__ void zero2(float* commitAcc, unsigned* bar) {
  commitAcc[0] = 0.f;
  bar[0] = 0u;
}

__global__ void finalize_com(const float* __restrict__ a, float* __restrict__ o) {
  o[0] = a[0] * (1.0f / (float)((size_t)NQUANT * BT * DDIM));
}

// ---------------------------------------------------------------------------
// Bounded-spin grid phase barrier. Purely a CACHE-PHASING device: no data
// crosses it, so a timeout exit is safe (perf-only). Counter is monotonic;
// after the k-th barrier all 256 blocks have added k each -> target k*256.
// ---------------------------------------------------------------------------
__device__ __forceinline__ void phase_barrier(unsigned* bar, unsigned gen,
                                              unsigned nblk) {
  __syncthreads();
  if (threadIdx.x == 0) {
    __threadfence();
    atomicAdd(bar, 1u);
    const unsigned target = gen * nblk;
    int spins = 0;
    while (__hip_atomic_load(bar, __ATOMIC_RELAXED, __HIP_MEMORY_SCOPE_AGENT) < target &&
           spins < 16384) {
      ++spins;
      __builtin_amdgcn_s_sleep(4);
    }
  }
  __syncthreads();
}

// ---------------------------------------------------------------------------
// Fused 8-step RVQ, no-spill layout. Grid 256 (1 block/CU), 8 waves/block.
// Wave w owns tokens [m0+w*16, +16): af[16] (hi 0-7, lo 8-15) = 64 VGPR.
// All waves sweep the full chunk (64 codes x 16 chunks) -> L1-shared B lines.
// B fragments double-buffered in registers. Per chunk: t0-3 hi_r*lo_c,
// t4-7 lo_r*hi_c, rescale 1/64, t8-11 hi_r*hi_c. Register argmin across all
// chunks; in-wave shfl reduce; in-register residual update with exact f32
// code gather. Phase barrier per step keeps the 1 MB/step codebook L2-hot.
// ---------------------------------------------------------------------------
__global__ __launch_bounds__(512, 2) void rvq_fused2(
    const f16* __restrict__ rext, const f16* __restrict__ cbext,
    const float* __restrict__ cbf32, const float* __restrict__ cnorm,
    float* __restrict__ qsum, float* __restrict__ q1, float* __restrict__ q2,
    float* __restrict__ commitAcc, unsigned* __restrict__ bar) {
  __shared__ float redc[512];
  const int tid = threadIdx.x;
  const int w = tid >> 6, l = tid & 63;
  const int lj = l & 15, li = l >> 4;
  const int m0 = blockIdx.x * 128;
  const int row = m0 + w * 16 + lj;        // this lane's token row (A layout)

  f16x8 af[16];
#pragma unroll
  for (int s = 0; s < 16; ++s)
    af[s] = *(const f16x8*)&rext[(size_t)row * 512 + s * 32 + li * 8];

  float csum = 0.f;

#pragma unroll 1
  for (int nq = 0; nq < NQUANT; ++nq) {
    if (nq > 0) phase_barrier(bar, (unsigned)nq, gridDim.x);
    const f16* cbq = cbext + (size_t)nq * KCODE * 512;
    const float* cnq = cnorm + nq * KCODE;

    float bval[4]; int bidxr[4];
#pragma unroll
    for (int j = 0; j < 4; ++j) { bval[j] = 3.0e38f; bidxr[j] = 0; }

    auto loadB = [&](f16x8 (*bf)[2], int chunk, int t) {
      const int tl = (t < 4) ? t : (t < 8 ? t - 4 : t - 8);
      const int kB = (t < 4) ? (256 + tl * 64) : (tl * 64);
#pragma unroll
      for (int n = 0; n < 4; ++n) {
        const int code = chunk * 64 + n * 16 + lj;
#pragma unroll
        for (int kk = 0; kk < 2; ++kk)
          bf[n][kk] = *(const f16x8*)&cbq[(size_t)code * 512 + kB + kk * 32 + li * 8];
      }
    };

#pragma unroll 1
    for (int chunk = 0; chunk < 16; ++chunk) {
      f32x4 acc[4];
#pragma unroll
      for (int n = 0; n < 4; ++n) acc[n] = (f32x4){0.f, 0.f, 0.f, 0.f};

      f16x8 b0[4][2], b1[4][2];
      loadB(b0, chunk, 0);
#pragma unroll
      for (int t = 0; t < 12; ++t) {
        f16x8 (*cur)[2] = (t & 1) ? b1 : b0;
        f16x8 (*nxt)[2] = (t & 1) ? b0 : b1;
        if (t < 11) loadB(nxt, chunk, t + 1);
        const int tl = (t < 4) ? t : (t < 8 ? t - 4 : t - 8);
        const int abase = (t >= 4 && t < 8) ? (8 + 2 * tl) : (2 * tl);
#pragma unroll
        for (int n = 0; n < 4; ++n)
#pragma unroll
          for (int kk = 0; kk < 2; ++kk)
            acc[n] = __builtin_amdgcn_mfma_f32_16x16x32_f16(af[abase + kk], cur[n][kk], acc[n], 0, 0, 0);
        if (t == 7) {
#pragma unroll
          for (int n = 0; n < 4; ++n)
#pragma unroll
            for (int j = 0; j < 4; ++j) acc[n][j] *= LO_INV;
        }
      }
      // distances + running argmin (ascending n -> first-occurrence tie-break)
#pragma unroll
      for (int n = 0; n < 4; ++n) {
        const int cl = chunk * 64 + n * 16 + lj;
        const float cn = cnq[cl];
#pragma unroll
        for (int j = 0; j < 4; ++j) {
          const float d = cn - 2.0f * acc[n][j];
          if (d < bval[j]) { bval[j] = d; bidxr[j] = cl; }
        }
      }
    }

    // reduce over the 16-lane code axis (lexicographic (val, idx) min)
#pragma unroll
    for (int off = 1; off < 16; off <<= 1) {
#pragma unroll
      for (int j = 0; j < 4; ++j) {
        const float ov = __shfl_xor(bval[j], off);
        const int oi = __shfl_xor(bidxr[j], off);
        if (ov < bval[j] || (ov == bval[j] && oi < bidxr[j])) {
          bval[j] = ov; bidxr[j] = oi;
        }
      }
    }
    // broadcast: code of token t16 lives in lanes li==t16>>2, register t16&3.
    // This lane updates token t16 = lj (A-fragment layout).
    const int src = (lj >> 2) * 16;
    const int c0 = __shfl(bidxr[0], src);
    const int c1 = __shfl(bidxr[1], src);
    const int c2 = __shfl(bidxr[2], src);
    const int c3 = __shfl(bidxr[3], src);
    const int sel = lj & 3;
    const int myCode = (sel == 0) ? c0 : (sel == 1) ? c1 : (sel == 2) ? c2 : c3;

    // in-register residual update + q1/q2 emission (exact f32 code row)
    const float* qrow = cbf32 + ((size_t)nq * KCODE + myCode) * DDIM;
#pragma unroll
    for (int s = 0; s < 8; ++s) {
      const f32x8 qv = *(const f32x8*)&qrow[s * 32 + li * 8];
      f16x8 h = af[s], lo = af[8 + s];
#pragma unroll
      for (int i = 0; i < 8; ++i) {
        const float rold = (float)h[i] + (float)lo[i] * LO_INV;
        const float diff = qv[i] - rold;
        csum += diff * diff;
        const float rnew = rold - qv[i];
        const f16 nh = (f16)rnew;
        h[i] = nh;
        lo[i] = (f16)((rnew - (float)nh) * LO_SCALE);
      }
      af[s] = h; af[8 + s] = lo;
      if (nq == 0)
        *(f32x8*)&q1[(size_t)row * DDIM + s * 32 + li * 8] = qv;
      if (nq == 1)
        *(f32x8*)&q2[(size_t)row * DDIM + s * 32 + li * 8] = qv;
    }
  }

  // qsum = h - r_final (h re-read from untouched rext)
#pragma unroll
  for (int s = 0; s < 8; ++s) {
    const f16x8 hh = *(const f16x8*)&rext[(size_t)row * 512 + s * 32 + li * 8];
    const f16x8 hl = *(const f16x8*)&rext[(size_t)row * 512 + 256 + s * 32 + li * 8];
    f32x8 o;
#pragma unroll
    for (int i = 0; i < 8; ++i)
      o[i] = ((float)hh[i] + (float)hl[i] * LO_INV) -
             ((float)af[s][i] + (float)af[8 + s][i] * LO_INV);
    *(f32x8*)&qsum[(size_t)row * DDIM + s * 32 + li * 8] = o;
  }

  redc[tid] = csum;
  __syncthreads();
  for (int s = 256; s > 0; s >>= 1) {
    if (tid < s) redc[tid] += redc[tid + s];
    __syncthreads();
  }
  if (tid == 0) atomicAdd(commitAcc, redc[0]);
}

// ---------------------------------------------------------------------------
// MFMA projection, no-spill layout. Grid (BT/128, N/64), 8 waves/block.
// Wave w owns rows [m0+w*16,+16); block covers 64 output cols.
// A f32 -> hi/lo split in registers per 256-K panel; B (Wext) from global
// (L2-resident), double-buffered. WEXT: write f16 hi/lo (proj_in) else f32.
// ---------------------------------------------------------------------------
template <int K, bool WEXT>
__global__ __launch_bounds__(512, 2) void proj2(
    const float* __restrict__ A, const f16* __restrict__ Bext,
    const float* __restrict__ bias, float* __restrict__ Cout,
    f16* __restrict__ CextOut, int Ntot) {
  const int tid = threadIdx.x;
  const int w = tid >> 6, l = tid & 63;
  const int lj = l & 15, li = l >> 4;
  const int m0 = blockIdx.x * 128;
  const int n0 = blockIdx.y * 64;
  const int row = m0 + w * 16 + lj;

  f32x4 acc[4], acc2[4];
#pragma unroll
  for (int n = 0; n < 4; ++n) {
    acc[n] = (f32x4){0.f, 0.f, 0.f, 0.f};
    acc2[n] = (f32x4){0.f, 0.f, 0.f, 0.f};
  }

#pragma unroll 1
  for (int p = 0; p < K / 256; ++p) {
    f16x8 ahi[8], alo[8];
#pragma unroll
    for (int s = 0; s < 8; ++s) {
      const f32x8 v = *(const f32x8*)&A[(size_t)row * K + p * 256 + s * 32 + li * 8];
      f16x8 h, lo;
#pragma unroll
      for (int i = 0; i < 8; ++i) {
        const f16 hh = (f16)v[i];
        h[i] = hh;
        lo[i] = (f16)((v[i] - (float)hh) * LO_SCALE);
      }
      ahi[s] = h; alo[s] = lo;
    }

    auto loadB = [&](f16x8 (*bf)[2], int t) {
      const int tl = (t < 4) ? t : (t < 8 ? t - 4 : t - 8);
      const int kB = (t < 4) ? (K + p * 256 + tl * 64) : (p * 256 + tl * 64);
#pragma unroll
      for (int n = 0; n < 4; ++n) {
        const int nrow = n0 + n * 16 + lj;
#pragma unroll
        for (int kk = 0; kk < 2; ++kk)
          bf[n][kk] = *(const f16x8*)&Bext[(size_t)nrow * (2 * K) + kB + kk * 32 + li * 8];
      }
    };

    f16x8 b0[4][2], b1[4][2];
    loadB(b0, 0);
#pragma unroll
    for (int t = 0; t < 12; ++t) {
      f16x8 (*cur)[2] = (t & 1) ? b1 : b0;
      f16x8 (*nxt)[2] = (t & 1) ? b0 : b1;
      if (t < 11) loadB(nxt, t + 1);
      const int tl = (t < 4) ? t : (t < 8 ? t - 4 : t - 8);
#pragma unroll
      for (int n = 0; n < 4; ++n)
#pragma unroll
        for (int kk = 0; kk < 2; ++kk) {
          if (t < 4)
            acc2[n] = __builtin_amdgcn_mfma_f32_16x16x32_f16(ahi[2 * tl + kk], cur[n][kk], acc2[n], 0, 0, 0);
          else if (t < 8)
            acc2[n] = __builtin_amdgcn_mfma_f32_16x16x32_f16(alo[2 * tl + kk], cur[n][kk], acc2[n], 0, 0, 0);
          else
            acc[n] = __builtin_amdgcn_mfma_f32_16x16x32_f16(ahi[2 * tl + kk], cur[n][kk], acc[n], 0, 0, 0);
        }
    }
  }

#pragma unroll
  for (int n = 0; n < 4; ++n) {
    const int ncol = n0 + n * 16 + lj;
    const float bb = bias[ncol];
#pragma unroll
    for (int j = 0; j < 4; ++j) {
      const int tok = m0 + w * 16 + li * 4 + j;
      const float vv = acc[n][j] + acc2[n][j] * LO_INV + bb;
      if (WEXT) {
        const f16 hh = (f16)vv;
        CextOut[(size_t)tok * 512 + ncol] = hh;
        CextOut[(size_t)tok * 512 + 256 + ncol] = (f16)((vv - (float)hh) * LO_SCALE);
      } else {
        Cout[(size_t)tok * Ntot + ncol] = vv;
      }
    }
  }
}

extern "C" void kernel_launch(void* const* d_in, const int* in_sizes, int n_in,
                              void* d_out, int out_size, void* d_ws, size_t ws_size,
                              hipStream_t stream) {
  (void)in_sizes; (void)n_in; (void)out_size; (void)ws_size;
  const float* x     = (const float*)d_in[0];
  const float* W_in  = (const float*)d_in[1];
  const float* b_in  = (const float*)d_in[2];
  const float* W_out = (const float*)d_in[3];
  const float* b_out = (const float*)d_in[4];
  const float* cbs   = (const float*)d_in[5];

  float* out = (float*)d_out;                        // [BT, HIDDEN]
  float* q1  = out + (size_t)BT * HIDDEN;            // [BT, DDIM]
  float* q2  = q1 + (size_t)BT * DDIM;               // [BT, DDIM]
  float* com = q2 + (size_t)BT * DDIM;               // [1]

  f16*   rext      = (f16*)d_ws;                          // [BT][512]   32 MB
  float* qsum      = (float*)(rext + (size_t)BT * 512);   // [BT][256]   32 MB
  f16*   cbext     = (f16*)(qsum + (size_t)BT * DDIM);    // [8192][512]  8 MB
  f16*   W_inext   = cbext + (size_t)NQUANT * KCODE * 512; // [256][1024] 512 KB
  f16*   W_outext  = W_inext + (size_t)DDIM * 1024;        // [512][512]  512 KB
  float* cnorm     = (float*)(W_outext + (size_t)HIDDEN * 512);  // [NQ*K]
  float* commitAcc = cnorm + NQUANT * KCODE;
  unsigned* bar    = (unsigned*)(commitAcc + 1);

  cnorm_kernel<<<NQUANT * KCODE, 256, 0, stream>>>(cbs, cnorm);
  cbext_conv<<<NQUANT * KCODE, 256, 0, stream>>>(cbs, cbext);
  bext_conv<<<(DDIM * HIDDEN + 255) / 256, 256, 0, stream>>>(W_in, W_inext, DDIM, HIDDEN);
  bext_conv<<<(HIDDEN * DDIM + 255) / 256, 256, 0, stream>>>(W_out, W_outext, HIDDEN, DDIM);
  proj2<HIDDEN, true><<<dim3(BT / 128, DDIM / 64), 512, 0, stream>>>(
      x, W_inext, b_in, nullptr, rext, DDIM);
  zero2<<<1, 1, 0, stream>>>(commitAcc, bar);
  rvq_fused2<<<BT / 128, 512, 0, stream>>>(rext, cbext, cbs, cnorm,
                                           qsum, q1, q2, commitAcc, bar);
  proj2<DDIM, false><<<dim3(BT / 128, HIDDEN / 64), 512, 0, stream>>>(
      qsum, W_outext, b_out, out, nullptr, HIDDEN);
  finalize_com<<<1, 1, 0, stream>>>(commitAcc, com);
}

// Round 6
// 1307.107 us; speedup vs baseline: 1.7106x; 1.7106x over previous
//
#include <hip/hip_runtime.h>

#define BT     32768
#define HIDDEN 512
#define DDIM   256
#define KCODE  1024
#define NQUANT 8

typedef _Float16 f16;
typedef _Float16 f16x8 __attribute__((ext_vector_type(8)));
typedef float f32x4 __attribute__((ext_vector_type(4)));
typedef float f32x8 __attribute__((ext_vector_type(8)));

#define LO_SCALE 64.0f
#define LO_INV   0.015625f

// ---------------------------------------------------------------------------
// cnorm: ||c||^2 for all NQ*K codes (fp32 exact)
// ---------------------------------------------------------------------------
__global__ __launch_bounds__(256) void cnorm_kernel(const float* __restrict__ cb,
                                                    float* __restrict__ cnorm) {
  __shared__ float red[256];
  const int code = blockIdx.x;
  const float v = cb[(size_t)code * DDIM + threadIdx.x];
  red[threadIdx.x] = v * v;
  __syncthreads();
  for (int s = 128; s > 0; s >>= 1) {
    if (threadIdx.x < s) red[threadIdx.x] += red[threadIdx.x + s];
    __syncthreads();
  }
  if (threadIdx.x == 0) cnorm[code] = red[0];
}

// ---------------------------------------------------------------------------
// codebooks -> f16 hi/lo ext: cbext[c][0..255]=hi, [256..511]=lo*64
// ---------------------------------------------------------------------------
__global__ __launch_bounds__(256) void cbext_conv(const float* __restrict__ cb,
                                                  f16* __restrict__ cbext) {
  const size_t idx = (size_t)blockIdx.x * 256 + threadIdx.x;
  const size_t c = idx >> 8;
  const int d = (int)(idx & 255);
  const float v = cb[idx];
  const f16 hi = (f16)v;
  cbext[c * 512 + d] = hi;
  cbext[c * 512 + 256 + d] = (f16)((v - (float)hi) * LO_SCALE);
}

// ---------------------------------------------------------------------------
// weight -> f16 hi/lo ext: Wext[n][0..K-1]=hi, [K..2K-1]=lo*64
// ---------------------------------------------------------------------------
__global__ __launch_bounds__(256) void bext_conv(const float* __restrict__ W,
                                                 f16* __restrict__ Wext,
                                                 int N, int K) {
  const int idx = blockIdx.x * 256 + threadIdx.x;
  if (idx >= N * K) return;
  const int n = idx / K, k = idx - n * K;
  const float v = W[idx];
  const f16 hi = (f16)v;
  Wext[(size_t)n * 2 * K + k] = hi;
  Wext[(size_t)n * 2 * K + K + k] = (f16)((v - (float)hi) * LO_SCALE);
}

__global__ void zero2(float* commitAcc, unsigned* bar) {
  commitAcc[0] = 0.f;
  bar[0] = 0u;
}

__global__ void finalize_com(const float* __restrict__ a, float* __restrict__ o) {
  o[0] = a[0] * (1.0f / (float)((size_t)NQUANT * BT * DDIM));
}

// ---------------------------------------------------------------------------
// Bounded-spin grid phase barrier (cache-phasing only; timeout-safe).
// ---------------------------------------------------------------------------
__device__ __forceinline__ void phase_barrier(unsigned* bar, unsigned gen,
                                              unsigned nblk) {
  __syncthreads();
  if (threadIdx.x == 0) {
    __threadfence();
    atomicAdd(bar, 1u);
    const unsigned target = gen * nblk;
    int spins = 0;
    while (__hip_atomic_load(bar, __ATOMIC_RELAXED, __HIP_MEMORY_SCOPE_AGENT) < target &&
           spins < 16384) {
      ++spins;
      __builtin_amdgcn_s_sleep(4);
    }
  }
  __syncthreads();
}

// ---------------------------------------------------------------------------
// Fused 8-step RVQ, LDS-broadcast B. Grid 256 x 512 thr (8 waves).
// Waves = 4 token-groups (wr) x 2 code-halves (wc). Wave owns 32 tokens in
// registers (af[2][16], hi slices 0-7 / lo 8-15) for the whole cascade and
// sweeps its 512-code half in 16 chunks of 32 codes.
// B: chunk-pair (64 code-rows x 1 KB) staged global->LDS via global_load_lds
// width 16, double-buffered, XOR-swizzled (byte ^= (row&7)<<4; inverse
// swizzle pre-applied on the per-lane global source). ds_read_b128 reads.
// Per chunk: t0-3 hi_r*lo_c, t4-7 lo_r*hi_c, rescale 1/64, t8-11 hi_r*hi_c.
// Register argmin (first-occurrence), shfl reduce, wc-merge in LDS,
// in-register residual update with exact f32 code gather.
// ---------------------------------------------------------------------------
__global__ __launch_bounds__(512, 2) void rvq_fused3(
    const f16* __restrict__ rext, const f16* __restrict__ cbext,
    const float* __restrict__ cbf32, const float* __restrict__ cnorm,
    float* __restrict__ qsum, float* __restrict__ q1, float* __restrict__ q2,
    float* __restrict__ commitAcc, unsigned* __restrict__ bar) {
  __shared__ __align__(16) f16 Bs[2][64][512];   // 128 KB
  __shared__ float mv[2][128];
  __shared__ int   mi[2][128];
  __shared__ int   bidx[128];
  __shared__ float redc[512];
  const int tid = threadIdx.x;
  const int w = tid >> 6, l = tid & 63;
  const int wr = w >> 1, wc = w & 1;
  const int lj = l & 15, li = l >> 4;
  const int m0 = blockIdx.x * 128;
  const int key = (lj & 7) << 4;                 // read-side swizzle key

  // residual fragments: af[m][s], token row = m0 + wr*32 + m*16 + lj
  f16x8 af[2][16];
#pragma unroll
  for (int m = 0; m < 2; ++m) {
    const int row = m0 + wr * 32 + m * 16 + lj;
#pragma unroll
    for (int s = 0; s < 16; ++s)
      af[m][s] = *(const f16x8*)&rext[(size_t)row * 512 + s * 32 + li * 8];
  }

  float csum = 0.f;

#pragma unroll 1
  for (int nq = 0; nq < NQUANT; ++nq) {
    if (nq > 0) phase_barrier(bar, (unsigned)nq, gridDim.x);
    const f16* cbq = cbext + (size_t)nq * KCODE * 512;
    const float* cnq = cnorm + nq * KCODE;

    // stage chunk-pair: row r (0..63) -> half h=r>>5, code h*512+chunk*32+(r&31)
    auto STAGE = [&](int chunk, int buf) {
#pragma unroll
      for (int q = 0; q < 8; ++q) {
        const int row = w * 8 + q;
        const int code = (row >> 5) * 512 + chunk * 32 + (row & 31);
        const char* src = (const char*)(cbq + ((size_t)code << 9)) +
                          ((l * 16) ^ ((row & 7) << 4));
        __builtin_amdgcn_global_load_lds(
            (const __attribute__((address_space(1))) void*)src,
            (__attribute__((address_space(3))) void*)&Bs[buf][row][0], 16, 0, 0);
      }
    };

    float bval[2][4]; int bidxr[2][4];
#pragma unroll
    for (int m = 0; m < 2; ++m)
#pragma unroll
      for (int j = 0; j < 4; ++j) { bval[m][j] = 3.0e38f; bidxr[m][j] = 0; }

    STAGE(0, 0);
    __syncthreads();                             // drains vmcnt before barrier
    int buf = 0;

#pragma unroll 1
    for (int c = 0; c < 16; ++c) {
      if (c < 15) STAGE(c + 1, buf ^ 1);
      f32x4 acc[2][2];
#pragma unroll
      for (int m = 0; m < 2; ++m)
#pragma unroll
        for (int n = 0; n < 2; ++n) acc[m][n] = (f32x4){0.f, 0.f, 0.f, 0.f};

#pragma unroll
      for (int t = 0; t < 12; ++t) {
        const int tl = (t < 4) ? t : (t < 8 ? t - 4 : t - 8);
        const int roff = (t < 4) ? 512 : 0;      // byte offset: lo | hi | hi
        const int abase = (t >= 4 && t < 8) ? (8 + 2 * tl) : (2 * tl);
        f16x8 bf[2][2];
#pragma unroll
        for (int n = 0; n < 2; ++n) {
          const int rr = wc * 32 + n * 16 + lj;
#pragma unroll
          for (int kk = 0; kk < 2; ++kk) {
            const int boff = roff + tl * 128 + kk * 64 + li * 16;
            bf[n][kk] = *(const f16x8*)((const char*)&Bs[buf][rr][0] + (boff ^ key));
          }
        }
#pragma unroll
        for (int m = 0; m < 2; ++m)
#pragma unroll
          for (int n = 0; n < 2; ++n)
#pragma unroll
            for (int kk = 0; kk < 2; ++kk)
              acc[m][n] = __builtin_amdgcn_mfma_f32_16x16x32_f16(
                  af[m][abase + kk], bf[n][kk], acc[m][n], 0, 0, 0);
        if (t == 7) {
#pragma unroll
          for (int m = 0; m < 2; ++m)
#pragma unroll
            for (int n = 0; n < 2; ++n)
#pragma unroll
              for (int j = 0; j < 4; ++j) acc[m][n][j] *= LO_INV;
        }
      }
      // distances + running argmin (ascending order -> first-occurrence)
#pragma unroll
      for (int n = 0; n < 2; ++n) {
        const int cl = wc * 512 + c * 32 + n * 16 + lj;
        const float cn = cnq[cl];
#pragma unroll
        for (int m = 0; m < 2; ++m)
#pragma unroll
          for (int j = 0; j < 4; ++j) {
            const float d = cn - 2.0f * acc[m][n][j];
            if (d < bval[m][j]) { bval[m][j] = d; bidxr[m][j] = cl; }
          }
      }
      __syncthreads();                           // staging done + buf reads done
      buf ^= 1;
    }

    // reduce over the 16-lane code axis (lexicographic (val, idx) min)
#pragma unroll
    for (int off = 1; off < 16; off <<= 1) {
#pragma unroll
      for (int m = 0; m < 2; ++m)
#pragma unroll
        for (int j = 0; j < 4; ++j) {
          const float ov = __shfl_xor(bval[m][j], off);
          const int oi = __shfl_xor(bidxr[m][j], off);
          if (ov < bval[m][j] || (ov == bval[m][j] && oi < bidxr[m][j])) {
            bval[m][j] = ov; bidxr[m][j] = oi;
          }
        }
    }
    if (lj == 0) {
#pragma unroll
      for (int m = 0; m < 2; ++m)
#pragma unroll
        for (int j = 0; j < 4; ++j) {
          const int tok = wr * 32 + m * 16 + li * 4 + j;
          mv[wc][tok] = bval[m][j]; mi[wc][tok] = bidxr[m][j];
        }
    }
    __syncthreads();
    if (tid < 128) {                             // wc0 codes < wc1 codes
      float v0 = mv[0][tid]; int i0 = mi[0][tid];
      if (mv[1][tid] < v0) { v0 = mv[1][tid]; i0 = mi[1][tid]; }
      bidx[tid] = i0;
    }
    __syncthreads();

    // in-register residual update (both wc copies) + q1/q2 (wc==0 only)
#pragma unroll
    for (int m = 0; m < 2; ++m) {
      const int tokl = wr * 32 + m * 16 + lj;
      const int code = bidx[tokl];
      const float* qrow = cbf32 + ((size_t)nq * KCODE + code) * DDIM;
#pragma unroll
      for (int s = 0; s < 8; ++s) {
        const f32x8 qv = *(const f32x8*)&qrow[s * 32 + li * 8];
        f16x8 h = af[m][s], lo = af[m][8 + s];
#pragma unroll
        for (int i = 0; i < 8; ++i) {
          const float rold = (float)h[i] + (float)lo[i] * LO_INV;
          const float diff = qv[i] - rold;
          if (wc == 0) csum += diff * diff;
          const float rnew = rold - qv[i];
          const f16 nh = (f16)rnew;
          h[i] = nh;
          lo[i] = (f16)((rnew - (float)nh) * LO_SCALE);
        }
        af[m][s] = h; af[m][8 + s] = lo;
        if (wc == 0 && nq == 0)
          *(f32x8*)&q1[(size_t)(m0 + tokl) * DDIM + s * 32 + li * 8] = qv;
        if (wc == 0 && nq == 1)
          *(f32x8*)&q2[(size_t)(m0 + tokl) * DDIM + s * 32 + li * 8] = qv;
      }
    }
    __syncthreads();                             // protect mv/mi/bidx
  }

  // qsum = h - r_final (h re-read from untouched rext); wc==0 writes
  if (wc == 0) {
#pragma unroll
    for (int m = 0; m < 2; ++m) {
      const int row = m0 + wr * 32 + m * 16 + lj;
#pragma unroll
      for (int s = 0; s < 8; ++s) {
        const f16x8 hh = *(const f16x8*)&rext[(size_t)row * 512 + s * 32 + li * 8];
        const f16x8 hl = *(const f16x8*)&rext[(size_t)row * 512 + 256 + s * 32 + li * 8];
        f32x8 o;
#pragma unroll
        for (int i = 0; i < 8; ++i)
          o[i] = ((float)hh[i] + (float)hl[i] * LO_INV) -
                 ((float)af[m][s][i] + (float)af[m][8 + s][i] * LO_INV);
        *(f32x8*)&qsum[(size_t)row * DDIM + s * 32 + li * 8] = o;
      }
    }
  }

  redc[tid] = csum;
  __syncthreads();
  for (int s = 256; s > 0; s >>= 1) {
    if (tid < s) redc[tid] += redc[tid + s];
    __syncthreads();
  }
  if (tid == 0) atomicAdd(commitAcc, redc[0]);
}

// ---------------------------------------------------------------------------
// MFMA projection (round-5 layout, unchanged). Grid (BT/128, N/64), 8 waves.
// ---------------------------------------------------------------------------
template <int K, bool WEXT>
__global__ __launch_bounds__(512, 2) void proj2(
    const float* __restrict__ A, const f16* __restrict__ Bext,
    const float* __restrict__ bias, float* __restrict__ Cout,
    f16* __restrict__ CextOut, int Ntot) {
  const int tid = threadIdx.x;
  const int w = tid >> 6, l = tid & 63;
  const int lj = l & 15, li = l >> 4;
  const int m0 = blockIdx.x * 128;
  const int n0 = blockIdx.y * 64;
  const int row = m0 + w * 16 + lj;

  f32x4 acc[4], acc2[4];
#pragma unroll
  for (int n = 0; n < 4; ++n) {
    acc[n] = (f32x4){0.f, 0.f, 0.f, 0.f};
    acc2[n] = (f32x4){0.f, 0.f, 0.f, 0.f};
  }

#pragma unroll 1
  for (int p = 0; p < K / 256; ++p) {
    f16x8 ahi[8], alo[8];
#pragma unroll
    for (int s = 0; s < 8; ++s) {
      const f32x8 v = *(const f32x8*)&A[(size_t)row * K + p * 256 + s * 32 + li * 8];
      f16x8 h, lo;
#pragma unroll
      for (int i = 0; i < 8; ++i) {
        const f16 hh = (f16)v[i];
        h[i] = hh;
        lo[i] = (f16)((v[i] - (float)hh) * LO_SCALE);
      }
      ahi[s] = h; alo[s] = lo;
    }

    auto loadB = [&](f16x8 (*bf)[2], int t) {
      const int tl = (t < 4) ? t : (t < 8 ? t - 4 : t - 8);
      const int kB = (t < 4) ? (K + p * 256 + tl * 64) : (p * 256 + tl * 64);
#pragma unroll
      for (int n = 0; n < 4; ++n) {
        const int nrow = n0 + n * 16 + lj;
#pragma unroll
        for (int kk = 0; kk < 2; ++kk)
          bf[n][kk] = *(const f16x8*)&Bext[(size_t)nrow * (2 * K) + kB + kk * 32 + li * 8];
      }
    };

    f16x8 b0[4][2], b1[4][2];
    loadB(b0, 0);
#pragma unroll
    for (int t = 0; t < 12; ++t) {
      f16x8 (*cur)[2] = (t & 1) ? b1 : b0;
      f16x8 (*nxt)[2] = (t & 1) ? b0 : b1;
      if (t < 11) loadB(nxt, t + 1);
      const int tl = (t < 4) ? t : (t < 8 ? t - 4 : t - 8);
#pragma unroll
      for (int n = 0; n < 4; ++n)
#pragma unroll
        for (int kk = 0; kk < 2; ++kk) {
          if (t < 4)
            acc2[n] = __builtin_amdgcn_mfma_f32_16x16x32_f16(ahi[2 * tl + kk], cur[n][kk], acc2[n], 0, 0, 0);
          else if (t < 8)
            acc2[n] = __builtin_amdgcn_mfma_f32_16x16x32_f16(alo[2 * tl + kk], cur[n][kk], acc2[n], 0, 0, 0);
          else
            acc[n] = __builtin_amdgcn_mfma_f32_16x16x32_f16(ahi[2 * tl + kk], cur[n][kk], acc[n], 0, 0, 0);
        }
    }
  }

#pragma unroll
  for (int n = 0; n < 4; ++n) {
    const int ncol = n0 + n * 16 + lj;
    const float bb = bias[ncol];
#pragma unroll
    for (int j = 0; j < 4; ++j) {
      const int tok = m0 + w * 16 + li * 4 + j;
      const float vv = acc[n][j] + acc2[n][j] * LO_INV + bb;
      if (WEXT) {
        const f16 hh = (f16)vv;
        CextOut[(size_t)tok * 512 + ncol] = hh;
        CextOut[(size_t)tok * 512 + 256 + ncol] = (f16)((vv - (float)hh) * LO_SCALE);
      } else {
        Cout[(size_t)tok * Ntot + ncol] = vv;
      }
    }
  }
}

extern "C" void kernel_launch(void* const* d_in, const int* in_sizes, int n_in,
                              void* d_out, int out_size, void* d_ws, size_t ws_size,
                              hipStream_t stream) {
  (void)in_sizes; (void)n_in; (void)out_size; (void)ws_size;
  const float* x     = (const float*)d_in[0];
  const float* W_in  = (const float*)d_in[1];
  const float* b_in  = (const float*)d_in[2];
  const float* W_out = (const float*)d_in[3];
  const float* b_out = (const float*)d_in[4];
  const float* cbs   = (const float*)d_in[5];

  float* out = (float*)d_out;                        // [BT, HIDDEN]
  float* q1  = out + (size_t)BT * HIDDEN;            // [BT, DDIM]
  float* q2  = q1 + (size_t)BT * DDIM;               // [BT, DDIM]
  float* com = q2 + (size_t)BT * DDIM;               // [1]

  f16*   rext      = (f16*)d_ws;                          // [BT][512]   32 MB
  float* qsum      = (float*)(rext + (size_t)BT * 512);   // [BT][256]   32 MB
  f16*   cbext     = (f16*)(qsum + (size_t)BT * DDIM);    // [8192][512]  8 MB
  f16*   W_inext   = cbext + (size_t)NQUANT * KCODE * 512; // [256][1024] 512 KB
  f16*   W_outext  = W_inext + (size_t)DDIM * 1024;        // [512][512]  512 KB
  float* cnorm     = (float*)(W_outext + (size_t)HIDDEN * 512);  // [NQ*K]
  float* commitAcc = cnorm + NQUANT * KCODE;
  unsigned* bar    = (unsigned*)(commitAcc + 1);

  cnorm_kernel<<<NQUANT * KCODE, 256, 0, stream>>>(cbs, cnorm);
  cbext_conv<<<NQUANT * KCODE, 256, 0, stream>>>(cbs, cbext);
  bext_conv<<<(DDIM * HIDDEN + 255) / 256, 256, 0, stream>>>(W_in, W_inext, DDIM, HIDDEN);
  bext_conv<<<(HIDDEN * DDIM + 255) / 256, 256, 0, stream>>>(W_out, W_outext, HIDDEN, DDIM);
  proj2<HIDDEN, true><<<dim3(BT / 128, DDIM / 64), 512, 0, stream>>>(
      x, W_inext, b_in, nullptr, rext, DDIM);
  zero2<<<1, 1, 0, stream>>>(commitAcc, bar);
  rvq_fused3<<<BT / 128, 512, 0, stream>>>(rext, cbext, cbs, cnorm,
                                           qsum, q1, q2, commitAcc, bar);
  proj2<DDIM, false><<<dim3(BT / 128, HIDDEN / 64), 512, 0, stream>>>(
      qsum, W_outext, b_out, out, nullptr, HIDDEN);
  finalize_com<<<1, 1, 0, stream>>>(commitAcc, com);
}

// Round 7
// 1208.351 us; speedup vs baseline: 1.8504x; 1.0817x over previous
//
#include <hip/hip_runtime.h>

#define BT     32768
#define HIDDEN 512
#define DDIM   256
#define KCODE  1024
#define NQUANT 8

typedef _Float16 f16;
typedef _Float16 f16x8 __attribute__((ext_vector_type(8)));
typedef float f32x4 __attribute__((ext_vector_type(4)));
typedef float f32x8 __attribute__((ext_vector_type(8)));

#define LO_SCALE 64.0f
#define LO_INV   0.015625f

// ---------------------------------------------------------------------------
// cnorm: ||c||^2 for all NQ*K codes (fp32 exact)
// ---------------------------------------------------------------------------
__global__ __launch_bounds__(256) void cnorm_kernel(const float* __restrict__ cb,
                                                    float* __restrict__ cnorm) {
  __shared__ float red[256];
  const int code = blockIdx.x;
  const float v = cb[(size_t)code * DDIM + threadIdx.x];
  red[threadIdx.x] = v * v;
  __syncthreads();
  for (int s = 128; s > 0; s >>= 1) {
    if (threadIdx.x < s) red[threadIdx.x] += red[threadIdx.x + s];
    __syncthreads();
  }
  if (threadIdx.x == 0) cnorm[code] = red[0];
}

// ---------------------------------------------------------------------------
// codebooks -> f16 hi/lo ext: cbext[c][0..255]=hi, [256..511]=lo*64
// ---------------------------------------------------------------------------
__global__ __launch_bounds__(256) void cbext_conv(const float* __restrict__ cb,
                                                  f16* __restrict__ cbext) {
  const size_t idx = (size_t)blockIdx.x * 256 + threadIdx.x;
  const size_t c = idx >> 8;
  const int d = (int)(idx & 255);
  const float v = cb[idx];
  const f16 hi = (f16)v;
  cbext[c * 512 + d] = hi;
  cbext[c * 512 + 256 + d] = (f16)((v - (float)hi) * LO_SCALE);
}

// ---------------------------------------------------------------------------
// weight -> f16 hi/lo ext: Wext[n][0..K-1]=hi, [K..2K-1]=lo*64
// ---------------------------------------------------------------------------
__global__ __launch_bounds__(256) void bext_conv(const float* __restrict__ W,
                                                 f16* __restrict__ Wext,
                                                 int N, int K) {
  const int idx = blockIdx.x * 256 + threadIdx.x;
  if (idx >= N * K) return;
  const int n = idx / K, k = idx - n * K;
  const float v = W[idx];
  const f16 hi = (f16)v;
  Wext[(size_t)n * 2 * K + k] = hi;
  Wext[(size_t)n * 2 * K + K + k] = (f16)((v - (float)hi) * LO_SCALE);
}

__global__ void zero2(float* commitAcc, unsigned* bar) {
  commitAcc[0] = 0.f;
  bar[0] = 0u;
}

__global__ void finalize_com(const float* __restrict__ a, float* __restrict__ o) {
  o[0] = a[0] * (1.0f / (float)((size_t)NQUANT * BT * DDIM));
}

// ---------------------------------------------------------------------------
// Bounded-spin grid phase barrier (cache-phasing only; timeout-safe).
// ---------------------------------------------------------------------------
__device__ __forceinline__ void phase_barrier(unsigned* bar, unsigned gen,
                                              unsigned nblk) {
  __syncthreads();
  if (threadIdx.x == 0) {
    __threadfence();
    atomicAdd(bar, 1u);
    const unsigned target = gen * nblk;
    int spins = 0;
    while (__hip_atomic_load(bar, __ATOMIC_RELAXED, __HIP_MEMORY_SCOPE_AGENT) < target &&
           spins < 16384) {
      ++spins;
      __builtin_amdgcn_s_sleep(4);
    }
  }
  __syncthreads();
}

// ---------------------------------------------------------------------------
// Fused 8-step RVQ, LDS-broadcast B. Identical to round 6 EXCEPT
// __launch_bounds__(512) (no occupancy minimum) so the allocator gets the
// full 256-VGPR budget: af[2][16] (128 VGPR) + bf + acc + argmin must stay
// in registers. LDS (132 KB) limits to 1 block/CU regardless.
// ---------------------------------------------------------------------------
__global__ __launch_bounds__(512) void rvq_fused4(
    const f16* __restrict__ rext, const f16* __restrict__ cbext,
    const float* __restrict__ cbf32, const float* __restrict__ cnorm,
    float* __restrict__ qsum, float* __restrict__ q1, float* __restrict__ q2,
    float* __restrict__ commitAcc, unsigned* __restrict__ bar) {
  __shared__ __align__(16) f16 Bs[2][64][512];   // 128 KB
  __shared__ float mv[2][128];
  __shared__ int   mi[2][128];
  __shared__ int   bidx[128];
  __shared__ float redc[512];
  const int tid = threadIdx.x;
  const int w = tid >> 6, l = tid & 63;
  const int wr = w >> 1, wc = w & 1;
  const int lj = l & 15, li = l >> 4;
  const int m0 = blockIdx.x * 128;
  const int key = (lj & 7) << 4;                 // read-side swizzle key

  f16x8 af[2][16];
#pragma unroll
  for (int m = 0; m < 2; ++m) {
    const int row = m0 + wr * 32 + m * 16 + lj;
#pragma unroll
    for (int s = 0; s < 16; ++s)
      af[m][s] = *(const f16x8*)&rext[(size_t)row * 512 + s * 32 + li * 8];
  }

  float csum = 0.f;

#pragma unroll 1
  for (int nq = 0; nq < NQUANT; ++nq) {
    if (nq > 0) phase_barrier(bar, (unsigned)nq, gridDim.x);
    const f16* cbq = cbext + (size_t)nq * KCODE * 512;
    const float* cnq = cnorm + nq * KCODE;

    auto STAGE = [&](int chunk, int buf) {
#pragma unroll
      for (int q = 0; q < 8; ++q) {
        const int row = w * 8 + q;
        const int code = (row >> 5) * 512 + chunk * 32 + (row & 31);
        const char* src = (const char*)(cbq + ((size_t)code << 9)) +
                          ((l * 16) ^ ((row & 7) << 4));
        __builtin_amdgcn_global_load_lds(
            (const __attribute__((address_space(1))) void*)src,
            (__attribute__((address_space(3))) void*)&Bs[buf][row][0], 16, 0, 0);
      }
    };

    float bval[2][4]; int bidxr[2][4];
#pragma unroll
    for (int m = 0; m < 2; ++m)
#pragma unroll
      for (int j = 0; j < 4; ++j) { bval[m][j] = 3.0e38f; bidxr[m][j] = 0; }

    STAGE(0, 0);
    __syncthreads();
    int buf = 0;

#pragma unroll 1
    for (int c = 0; c < 16; ++c) {
      if (c < 15) STAGE(c + 1, buf ^ 1);
      f32x4 acc[2][2];
#pragma unroll
      for (int m = 0; m < 2; ++m)
#pragma unroll
        for (int n = 0; n < 2; ++n) acc[m][n] = (f32x4){0.f, 0.f, 0.f, 0.f};

#pragma unroll
      for (int t = 0; t < 12; ++t) {
        const int tl = (t < 4) ? t : (t < 8 ? t - 4 : t - 8);
        const int roff = (t < 4) ? 512 : 0;
        const int abase = (t >= 4 && t < 8) ? (8 + 2 * tl) : (2 * tl);
        f16x8 bf[2][2];
#pragma unroll
        for (int n = 0; n < 2; ++n) {
          const int rr = wc * 32 + n * 16 + lj;
#pragma unroll
          for (int kk = 0; kk < 2; ++kk) {
            const int boff = roff + tl * 128 + kk * 64 + li * 16;
            bf[n][kk] = *(const f16x8*)((const char*)&Bs[buf][rr][0] + (boff ^ key));
          }
        }
#pragma unroll
        for (int m = 0; m < 2; ++m)
#pragma unroll
          for (int n = 0; n < 2; ++n)
#pragma unroll
            for (int kk = 0; kk < 2; ++kk)
              acc[m][n] = __builtin_amdgcn_mfma_f32_16x16x32_f16(
                  af[m][abase + kk], bf[n][kk], acc[m][n], 0, 0, 0);
        if (t == 7) {
#pragma unroll
          for (int m = 0; m < 2; ++m)
#pragma unroll
            for (int n = 0; n < 2; ++n)
#pragma unroll
              for (int j = 0; j < 4; ++j) acc[m][n][j] *= LO_INV;
        }
      }
#pragma unroll
      for (int n = 0; n < 2; ++n) {
        const int cl = wc * 512 + c * 32 + n * 16 + lj;
        const float cn = cnq[cl];
#pragma unroll
        for (int m = 0; m < 2; ++m)
#pragma unroll
          for (int j = 0; j < 4; ++j) {
            const float d = cn - 2.0f * acc[m][n][j];
            if (d < bval[m][j]) { bval[m][j] = d; bidxr[m][j] = cl; }
          }
      }
      __syncthreads();
      buf ^= 1;
    }

#pragma unroll
    for (int off = 1; off < 16; off <<= 1) {
#pragma unroll
      for (int m = 0; m < 2; ++m)
#pragma unroll
        for (int j = 0; j < 4; ++j) {
          const float ov = __shfl_xor(bval[m][j], off);
          const int oi = __shfl_xor(bidxr[m][j], off);
          if (ov < bval[m][j] || (ov == bval[m][j] && oi < bidxr[m][j])) {
            bval[m][j] = ov; bidxr[m][j] = oi;
          }
        }
    }
    if (lj == 0) {
#pragma unroll
      for (int m = 0; m < 2; ++m)
#pragma unroll
        for (int j = 0; j < 4; ++j) {
          const int tok = wr * 32 + m * 16 + li * 4 + j;
          mv[wc][tok] = bval[m][j]; mi[wc][tok] = bidxr[m][j];
        }
    }
    __syncthreads();
    if (tid < 128) {
      float v0 = mv[0][tid]; int i0 = mi[0][tid];
      if (mv[1][tid] < v0) { v0 = mv[1][tid]; i0 = mi[1][tid]; }
      bidx[tid] = i0;
    }
    __syncthreads();

#pragma unroll
    for (int m = 0; m < 2; ++m) {
      const int tokl = wr * 32 + m * 16 + lj;
      const int code = bidx[tokl];
      const float* qrow = cbf32 + ((size_t)nq * KCODE + code) * DDIM;
#pragma unroll
      for (int s = 0; s < 8; ++s) {
        const f32x8 qv = *(const f32x8*)&qrow[s * 32 + li * 8];
        f16x8 h = af[m][s], lo = af[m][8 + s];
#pragma unroll
        for (int i = 0; i < 8; ++i) {
          const float rold = (float)h[i] + (float)lo[i] * LO_INV;
          const float diff = qv[i] - rold;
          if (wc == 0) csum += diff * diff;
          const float rnew = rold - qv[i];
          const f16 nh = (f16)rnew;
          h[i] = nh;
          lo[i] = (f16)((rnew - (float)nh) * LO_SCALE);
        }
        af[m][s] = h; af[m][8 + s] = lo;
        if (wc == 0 && nq == 0)
          *(f32x8*)&q1[(size_t)(m0 + tokl) * DDIM + s * 32 + li * 8] = qv;
        if (wc == 0 && nq == 1)
          *(f32x8*)&q2[(size_t)(m0 + tokl) * DDIM + s * 32 + li * 8] = qv;
      }
    }
    __syncthreads();
  }

  if (wc == 0) {
#pragma unroll
    for (int m = 0; m < 2; ++m) {
      const int row = m0 + wr * 32 + m * 16 + lj;
#pragma unroll
      for (int s = 0; s < 8; ++s) {
        const f16x8 hh = *(const f16x8*)&rext[(size_t)row * 512 + s * 32 + li * 8];
        const f16x8 hl = *(const f16x8*)&rext[(size_t)row * 512 + 256 + s * 32 + li * 8];
        f32x8 o;
#pragma unroll
        for (int i = 0; i < 8; ++i)
          o[i] = ((float)hh[i] + (float)hl[i] * LO_INV) -
                 ((float)af[m][s][i] + (float)af[m][8 + s][i] * LO_INV);
        *(f32x8*)&qsum[(size_t)row * DDIM + s * 32 + li * 8] = o;
      }
    }
  }

  redc[tid] = csum;
  __syncthreads();
  for (int s = 256; s > 0; s >>= 1) {
    if (tid < s) redc[tid] += redc[tid + s];
    __syncthreads();
  }
  if (tid == 0) atomicAdd(commitAcc, redc[0]);
}

// ---------------------------------------------------------------------------
// Projection v3: LDS-staged B panel, rvq-style. Block = 128 tokens x 128
// cols, 8 waves each owning 16 tokens and sweeping all 128 cols.
// Per 256-K panel: stage 128 rows x [hi256|lo256] (1 KB/row, one
// global_load_lds issue per row: per-lane source covers both discontiguous
// segments; XOR-swizzled). Then the same 12-t hi/lo MFMA loop.
// t0-3: ahi*lo_c -> acc2; t4-7: alo*hi_c -> acc2; t8-11: ahi*hi_c -> acc.
// Epilogue: acc + acc2/64 + bias (order-identical to round-5 proj2).
// ---------------------------------------------------------------------------
template <int K, bool WEXT>
__global__ __launch_bounds__(512) void proj3(
    const float* __restrict__ A, const f16* __restrict__ Bext,
    const float* __restrict__ bias, float* __restrict__ Cout,
    f16* __restrict__ CextOut, int Ntot) {
  __shared__ __align__(16) f16 Bs[128][512];     // 128 KB
  const int tid = threadIdx.x;
  const int w = tid >> 6, l = tid & 63;
  const int lj = l & 15, li = l >> 4;
  const int m0 = blockIdx.x * 128;
  const int n0 = blockIdx.y * 128;
  const int row_t = m0 + w * 16 + lj;            // this lane's token row
  const int key = (lj & 7) << 4;

  f32x4 acc[8], acc2[8];
#pragma unroll
  for (int n = 0; n < 8; ++n) {
    acc[n] = (f32x4){0.f, 0.f, 0.f, 0.f};
    acc2[n] = (f32x4){0.f, 0.f, 0.f, 0.f};
  }

#pragma unroll 1
  for (int p = 0; p < K / 256; ++p) {
    __syncthreads();                             // prev-panel reads complete
    // stage B panel: 16 rows per wave, one 1 KB issue per row
#pragma unroll
    for (int q = 0; q < 16; ++q) {
      const int row = w * 16 + q;
      const int nrow = n0 + row;
      const int byteoff = (l * 16) ^ ((row & 7) << 4);
      const char* hi_base =
          (const char*)Bext + ((size_t)nrow * 2 * K + p * 256) * 2;
      const char* lo_base =
          (const char*)Bext + ((size_t)nrow * 2 * K + K + p * 256) * 2;
      const char* src = (byteoff < 512) ? hi_base + byteoff
                                        : lo_base + (byteoff - 512);
      __builtin_amdgcn_global_load_lds(
          (const __attribute__((address_space(1))) void*)src,
          (__attribute__((address_space(3))) void*)&Bs[row][0], 16, 0, 0);
    }
    // A fragments for this panel (f32 -> hi/lo in registers)
    f16x8 ahi[8], alo[8];
#pragma unroll
    for (int s = 0; s < 8; ++s) {
      const f32x8 v = *(const f32x8*)&A[(size_t)row_t * K + p * 256 + s * 32 + li * 8];
      f16x8 h, lo;
#pragma unroll
      for (int i = 0; i < 8; ++i) {
        const f16 hh = (f16)v[i];
        h[i] = hh;
        lo[i] = (f16)((v[i] - (float)hh) * LO_SCALE);
      }
      ahi[s] = h; alo[s] = lo;
    }
    __syncthreads();                             // drains stage + A loads

#pragma unroll
    for (int t = 0; t < 12; ++t) {
      const int tl = (t < 4) ? t : (t < 8 ? t - 4 : t - 8);
      const int roff = (t < 4) ? 512 : 0;        // lo_c | hi_c | hi_c
#pragma unroll
      for (int n = 0; n < 8; ++n) {
        const int rr = n * 16 + lj;
#pragma unroll
        for (int kk = 0; kk < 2; ++kk) {
          const int boff = roff + tl * 128 + kk * 64 + li * 16;
          const f16x8 bf = *(const f16x8*)((const char*)&Bs[rr][0] + (boff ^ key));
          if (t < 4)
            acc2[n] = __builtin_amdgcn_mfma_f32_16x16x32_f16(ahi[2 * tl + kk], bf, acc2[n], 0, 0, 0);
          else if (t < 8)
            acc2[n] = __builtin_amdgcn_mfma_f32_16x16x32_f16(alo[2 * tl + kk], bf, acc2[n], 0, 0, 0);
          else
            acc[n] = __builtin_amdgcn_mfma_f32_16x16x32_f16(ahi[2 * tl + kk], bf, acc[n], 0, 0, 0);
        }
      }
    }
  }

#pragma unroll
  for (int n = 0; n < 8; ++n) {
    const int ncol = n0 + n * 16 + lj;
    const float bb = bias[ncol];
#pragma unroll
    for (int j = 0; j < 4; ++j) {
      const int tok = m0 + w * 16 + li * 4 + j;
      const float vv = acc[n][j] + acc2[n][j] * LO_INV + bb;
      if (WEXT) {
        const f16 hh = (f16)vv;
        CextOut[(size_t)tok * 512 + ncol] = hh;
        CextOut[(size_t)tok * 512 + 256 + ncol] = (f16)((vv - (float)hh) * LO_SCALE);
      } else {
        Cout[(size_t)tok * Ntot + ncol] = vv;
      }
    }
  }
}

extern "C" void kernel_launch(void* const* d_in, const int* in_sizes, int n_in,
                              void* d_out, int out_size, void* d_ws, size_t ws_size,
                              hipStream_t stream) {
  (void)in_sizes; (void)n_in; (void)out_size; (void)ws_size;
  const float* x     = (const float*)d_in[0];
  const float* W_in  = (const float*)d_in[1];
  const float* b_in  = (const float*)d_in[2];
  const float* W_out = (const float*)d_in[3];
  const float* b_out = (const float*)d_in[4];
  const float* cbs   = (const float*)d_in[5];

  float* out = (float*)d_out;                        // [BT, HIDDEN]
  float* q1  = out + (size_t)BT * HIDDEN;            // [BT, DDIM]
  float* q2  = q1 + (size_t)BT * DDIM;               // [BT, DDIM]
  float* com = q2 + (size_t)BT * DDIM;               // [1]

  f16*   rext      = (f16*)d_ws;                          // [BT][512]   32 MB
  float* qsum      = (float*)(rext + (size_t)BT * 512);   // [BT][256]   32 MB
  f16*   cbext     = (f16*)(qsum + (size_t)BT * DDIM);    // [8192][512]  8 MB
  f16*   W_inext   = cbext + (size_t)NQUANT * KCODE * 512; // [256][1024] 512 KB
  f16*   W_outext  = W_inext + (size_t)DDIM * 1024;        // [512][512]  512 KB
  float* cnorm     = (float*)(W_outext + (size_t)HIDDEN * 512);  // [NQ*K]
  float* commitAcc = cnorm + NQUANT * KCODE;
  unsigned* bar    = (unsigned*)(commitAcc + 1);

  cnorm_kernel<<<NQUANT * KCODE, 256, 0, stream>>>(cbs, cnorm);
  cbext_conv<<<NQUANT * KCODE, 256, 0, stream>>>(cbs, cbext);
  bext_conv<<<(DDIM * HIDDEN + 255) / 256, 256, 0, stream>>>(W_in, W_inext, DDIM, HIDDEN);
  bext_conv<<<(HIDDEN * DDIM + 255) / 256, 256, 0, stream>>>(W_out, W_outext, HIDDEN, DDIM);
  proj3<HIDDEN, true><<<dim3(BT / 128, DDIM / 128), 512, 0, stream>>>(
      x, W_inext, b_in, nullptr, rext, DDIM);
  zero2<<<1, 1, 0, stream>>>(commitAcc, bar);
  rvq_fused4<<<BT / 128, 512, 0, stream>>>(rext, cbext, cbs, cnorm,
                                           qsum, q1, q2, commitAcc, bar);
  proj3<DDIM, false><<<dim3(BT / 128, HIDDEN / 128), 512, 0, stream>>>(
      qsum, W_outext, b_out, out, nullptr, HIDDEN);
  finalize_com<<<1, 1, 0, stream>>>(commitAcc, com);
}

// Round 9
// 775.465 us; speedup vs baseline: 2.8833x; 1.5582x over previous
//
#include <hip/hip_runtime.h>

#define BT     32768
#define HIDDEN 512
#define DDIM   256
#define KCODE  1024
#define NQUANT 8

typedef _Float16 f16;
typedef _Float16 f16x8 __attribute__((ext_vector_type(8)));
typedef float f32x4 __attribute__((ext_vector_type(4)));
typedef float f32x8 __attribute__((ext_vector_type(8)));

#define LO_SCALE 64.0f
#define LO_INV   0.015625f

// ---------------------------------------------------------------------------
// cnorm: ||c||^2 for all NQ*K codes (fp32 exact)
// ---------------------------------------------------------------------------
__global__ __launch_bounds__(256) void cnorm_kernel(const float* __restrict__ cb,
                                                    float* __restrict__ cnorm) {
  __shared__ float red[256];
  const int code = blockIdx.x;
  const float v = cb[(size_t)code * DDIM + threadIdx.x];
  red[threadIdx.x] = v * v;
  __syncthreads();
  for (int s = 128; s > 0; s >>= 1) {
    if (threadIdx.x < s) red[threadIdx.x] += red[threadIdx.x + s];
    __syncthreads();
  }
  if (threadIdx.x == 0) cnorm[code] = red[0];
}

// ---------------------------------------------------------------------------
// codebooks -> f16 hi/lo ext: cbext[c][0..255]=hi, [256..511]=lo*64
// ---------------------------------------------------------------------------
__global__ __launch_bounds__(256) void cbext_conv(const float* __restrict__ cb,
                                                  f16* __restrict__ cbext) {
  const size_t idx = (size_t)blockIdx.x * 256 + threadIdx.x;
  const size_t c = idx >> 8;
  const int d = (int)(idx & 255);
  const float v = cb[idx];
  const f16 hi = (f16)v;
  cbext[c * 512 + d] = hi;
  cbext[c * 512 + 256 + d] = (f16)((v - (float)hi) * LO_SCALE);
}

// ---------------------------------------------------------------------------
// weight -> f16 hi/lo ext: Wext[n][0..K-1]=hi, [K..2K-1]=lo*64
// ---------------------------------------------------------------------------
__global__ __launch_bounds__(256) void bext_conv(const float* __restrict__ W,
                                                 f16* __restrict__ Wext,
                                                 int N, int K) {
  const int idx = blockIdx.x * 256 + threadIdx.x;
  if (idx >= N * K) return;
  const int n = idx / K, k = idx - n * K;
  const float v = W[idx];
  const f16 hi = (f16)v;
  Wext[(size_t)n * 2 * K + k] = hi;
  Wext[(size_t)n * 2 * K + K + k] = (f16)((v - (float)hi) * LO_SCALE);
}

__global__ void zero2(float* commitAcc, unsigned* bar) {
  commitAcc[0] = 0.f;
  bar[0] = 0u;
}

__global__ void finalize_com(const float* __restrict__ a, float* __restrict__ o) {
  o[0] = a[0] * (1.0f / (float)((size_t)NQUANT * BT * DDIM));
}

// ---------------------------------------------------------------------------
// Bounded-spin grid phase barrier (cache-phasing only; timeout-safe).
// ---------------------------------------------------------------------------
__device__ __forceinline__ void phase_barrier(unsigned* bar, unsigned gen,
                                              unsigned nblk) {
  __syncthreads();
  if (threadIdx.x == 0) {
    __threadfence();
    atomicAdd(bar, 1u);
    const unsigned target = gen * nblk;
    int spins = 0;
    while (__hip_atomic_load(bar, __ATOMIC_RELAXED, __HIP_MEMORY_SCOPE_AGENT) < target &&
           spins < 16384) {
      ++spins;
      __builtin_amdgcn_s_sleep(4);
    }
  }
  __syncthreads();
}

// ---------------------------------------------------------------------------
// Fused 8-step RVQ, no-spill + LDS-broadcast B.
// Block = 128 tokens, 8 waves; wave w owns tokens [m0+w*16, +16) in
// af[16] registers (hi slices 0-7, lo 8-15; 64 VGPR — R5-proven clean).
// Every wave sweeps all 1024 codes: 16 chunks of 64 codes staged
// global->LDS (global_load_lds w16, XOR swizzle byte^=(row&7)<<4 applied
// on both the pre-swizzled source and the read), double-buffered.
// Per chunk: t0-3 hi_r*lo_c, t4-7 lo_r*hi_c, *=1/64, t8-11 hi_r*hi_c.
// Register argmin over all chunks (first-occurrence), in-wave shfl
// reduce + broadcast, in-register residual update w/ exact f32 gather.
// All-builtin MFMA (inline-asm MFMA caused R8's NaN: hazard nops).
// ---------------------------------------------------------------------------
__global__ __launch_bounds__(512) void rvq_fused6(
    const f16* __restrict__ rext, const f16* __restrict__ cbext,
    const float* __restrict__ cbf32, const float* __restrict__ cnorm,
    float* __restrict__ qsum, float* __restrict__ q1, float* __restrict__ q2,
    float* __restrict__ commitAcc, unsigned* __restrict__ bar) {
  __shared__ __align__(16) f16 Bs[2][64][512];   // 128 KB
  __shared__ float redc[512];
  const int tid = threadIdx.x;
  const int w = tid >> 6, l = tid & 63;
  const int lj = l & 15, li = l >> 4;
  const int m0 = blockIdx.x * 128;
  const int row = m0 + w * 16 + lj;              // this lane's token row
  const int key = (lj & 7) << 4;                 // read-side swizzle key

  f16x8 af[16];
#pragma unroll
  for (int s = 0; s < 16; ++s)
    af[s] = *(const f16x8*)&rext[(size_t)row * 512 + s * 32 + li * 8];

  float csum = 0.f;

#pragma unroll 1
  for (int nq = 0; nq < NQUANT; ++nq) {
    if (nq > 0) phase_barrier(bar, (unsigned)nq, gridDim.x);
    const f16* cbq = cbext + (size_t)nq * KCODE * 512;
    const float* cnq = cnorm + nq * KCODE;

    // stage chunk c: LDS row r (0..63) <- code c*64 + r (1 KB, swizzled)
    auto STAGE = [&](int chunk, int buf) {
#pragma unroll
      for (int q = 0; q < 8; ++q) {
        const int r = w * 8 + q;
        const int code = chunk * 64 + r;
        const char* src = (const char*)(cbq + ((size_t)code << 9)) +
                          ((l * 16) ^ ((r & 7) << 4));
        __builtin_amdgcn_global_load_lds(
            (const __attribute__((address_space(1))) void*)src,
            (__attribute__((address_space(3))) void*)&Bs[buf][r][0], 16, 0, 0);
      }
    };

    float bval[4]; int bidxr[4];
#pragma unroll
    for (int j = 0; j < 4; ++j) { bval[j] = 3.0e38f; bidxr[j] = 0; }

    STAGE(0, 0);
    __syncthreads();
    int buf = 0;

#pragma unroll 1
    for (int c = 0; c < 16; ++c) {
      if (c < 15) STAGE(c + 1, buf ^ 1);
      f32x4 acc[4];
#pragma unroll
      for (int n = 0; n < 4; ++n) acc[n] = (f32x4){0.f, 0.f, 0.f, 0.f};

#pragma unroll
      for (int t = 0; t < 12; ++t) {
        const int tl = (t < 4) ? t : (t < 8 ? t - 4 : t - 8);
        const int roff = (t < 4) ? 512 : 0;      // lo_c | hi_c | hi_c
        const int abase = (t >= 4 && t < 8) ? (8 + 2 * tl) : (2 * tl);
        f16x8 bf[4][2];
#pragma unroll
        for (int n = 0; n < 4; ++n) {
          const int rr = n * 16 + lj;
#pragma unroll
          for (int kk = 0; kk < 2; ++kk) {
            const int boff = roff + tl * 128 + kk * 64 + li * 16;
            bf[n][kk] = *(const f16x8*)((const char*)&Bs[buf][rr][0] + (boff ^ key));
          }
        }
#pragma unroll
        for (int n = 0; n < 4; ++n)
#pragma unroll
          for (int kk = 0; kk < 2; ++kk)
            acc[n] = __builtin_amdgcn_mfma_f32_16x16x32_f16(
                af[abase + kk], bf[n][kk], acc[n], 0, 0, 0);
        if (t == 7) {
#pragma unroll
          for (int n = 0; n < 4; ++n)
#pragma unroll
            for (int j = 0; j < 4; ++j) acc[n][j] *= LO_INV;
        }
      }
      // distances + running argmin (ascending order -> first-occurrence)
#pragma unroll
      for (int n = 0; n < 4; ++n) {
        const int cl = c * 64 + n * 16 + lj;
        const float cn = cnq[cl];
#pragma unroll
        for (int j = 0; j < 4; ++j) {
          const float d = cn - 2.0f * acc[n][j];
          if (d < bval[j]) { bval[j] = d; bidxr[j] = cl; }
        }
      }
      __syncthreads();                           // staging done + reads done
      buf ^= 1;
    }

    // reduce over the 16-lane code axis (lexicographic (val, idx) min)
#pragma unroll
    for (int off = 1; off < 16; off <<= 1) {
#pragma unroll
      for (int j = 0; j < 4; ++j) {
        const float ov = __shfl_xor(bval[j], off);
        const int oi = __shfl_xor(bidxr[j], off);
        if (ov < bval[j] || (ov == bval[j] && oi < bidxr[j])) {
          bval[j] = ov; bidxr[j] = oi;
        }
      }
    }
    // broadcast: token t16's code lives in lanes li==t16>>2, register t16&3.
    // This lane updates token t16 = lj (A-fragment layout).  (R5-proven.)
    const int src = (lj >> 2) * 16;
    const int c0 = __shfl(bidxr[0], src);
    const int c1 = __shfl(bidxr[1], src);
    const int c2 = __shfl(bidxr[2], src);
    const int c3 = __shfl(bidxr[3], src);
    const int sel = lj & 3;
    const int myCode = (sel == 0) ? c0 : (sel == 1) ? c1 : (sel == 2) ? c2 : c3;

    // in-register residual update + q1/q2 emission (exact f32 code row)
    const float* qrow = cbf32 + ((size_t)nq * KCODE + myCode) * DDIM;
#pragma unroll
    for (int s = 0; s < 8; ++s) {
      const f32x8 qv = *(const f32x8*)&qrow[s * 32 + li * 8];
      f16x8 h = af[s], lo = af[8 + s];
#pragma unroll
      for (int i = 0; i < 8; ++i) {
        const float rold = (float)h[i] + (float)lo[i] * LO_INV;
        const float diff = qv[i] - rold;
        csum += diff * diff;
        const float rnew = rold - qv[i];
        const f16 nh = (f16)rnew;
        h[i] = nh;
        lo[i] = (f16)((rnew - (float)nh) * LO_SCALE);
      }
      af[s] = h; af[8 + s] = lo;
      if (nq == 0)
        *(f32x8*)&q1[(size_t)row * DDIM + s * 32 + li * 8] = qv;
      if (nq == 1)
        *(f32x8*)&q2[(size_t)row * DDIM + s * 32 + li * 8] = qv;
    }
  }

  // qsum = h - r_final (h re-read from untouched rext)
#pragma unroll
  for (int s = 0; s < 8; ++s) {
    const f16x8 hh = *(const f16x8*)&rext[(size_t)row * 512 + s * 32 + li * 8];
    const f16x8 hl = *(const f16x8*)&rext[(size_t)row * 512 + 256 + s * 32 + li * 8];
    f32x8 o;
#pragma unroll
    for (int i = 0; i < 8; ++i)
      o[i] = ((float)hh[i] + (float)hl[i] * LO_INV) -
             ((float)af[s][i] + (float)af[8 + s][i] * LO_INV);
    *(f32x8*)&qsum[(size_t)row * DDIM + s * 32 + li * 8] = o;
  }

  redc[tid] = csum;
  __syncthreads();
  for (int s = 256; s > 0; s >>= 1) {
    if (tid < s) redc[tid] += redc[tid + s];
    __syncthreads();
  }
  if (tid == 0) atomicAdd(commitAcc, redc[0]);
}

// ---------------------------------------------------------------------------
// Projection v3 (builtin MFMA — the R7-bench-passing version, unchanged).
// Block = 128 tokens x 128 cols, 8 waves x 16 tokens; B panel in LDS.
// ---------------------------------------------------------------------------
template <int K, bool WEXT>
__global__ __launch_bounds__(512) void proj3(
    const float* __restrict__ A, const f16* __restrict__ Bext,
    const float* __restrict__ bias, float* __restrict__ Cout,
    f16* __restrict__ CextOut, int Ntot) {
  __shared__ __align__(16) f16 Bs[128][512];     // 128 KB
  const int tid = threadIdx.x;
  const int w = tid >> 6, l = tid & 63;
  const int lj = l & 15, li = l >> 4;
  const int m0 = blockIdx.x * 128;
  const int n0 = blockIdx.y * 128;
  const int row_t = m0 + w * 16 + lj;
  const int key = (lj & 7) << 4;

  f32x4 acc[8], acc2[8];
#pragma unroll
  for (int n = 0; n < 8; ++n) {
    acc[n] = (f32x4){0.f, 0.f, 0.f, 0.f};
    acc2[n] = (f32x4){0.f, 0.f, 0.f, 0.f};
  }

#pragma unroll 1
  for (int p = 0; p < K / 256; ++p) {
    __syncthreads();
#pragma unroll
    for (int q = 0; q < 16; ++q) {
      const int r = w * 16 + q;
      const int nrow = n0 + r;
      const int byteoff = (l * 16) ^ ((r & 7) << 4);
      const char* hi_base =
          (const char*)Bext + ((size_t)nrow * 2 * K + p * 256) * 2;
      const char* lo_base =
          (const char*)Bext + ((size_t)nrow * 2 * K + K + p * 256) * 2;
      const char* src = (byteoff < 512) ? hi_base + byteoff
                                        : lo_base + (byteoff - 512);
      __builtin_amdgcn_global_load_lds(
          (const __attribute__((address_space(1))) void*)src,
          (__attribute__((address_space(3))) void*)&Bs[r][0], 16, 0, 0);
    }
    f16x8 ahi[8], alo[8];
#pragma unroll
    for (int s = 0; s < 8; ++s) {
      const f32x8 v = *(const f32x8*)&A[(size_t)row_t * K + p * 256 + s * 32 + li * 8];
      f16x8 h, lo;
#pragma unroll
      for (int i = 0; i < 8; ++i) {
        const f16 hh = (f16)v[i];
        h[i] = hh;
        lo[i] = (f16)((v[i] - (float)hh) * LO_SCALE);
      }
      ahi[s] = h; alo[s] = lo;
    }
    __syncthreads();

#pragma unroll
    for (int t = 0; t < 12; ++t) {
      const int tl = (t < 4) ? t : (t < 8 ? t - 4 : t - 8);
      const int roff = (t < 4) ? 512 : 0;
#pragma unroll
      for (int n = 0; n < 8; ++n) {
        const int rr = n * 16 + lj;
#pragma unroll
        for (int kk = 0; kk < 2; ++kk) {
          const int boff = roff + tl * 128 + kk * 64 + li * 16;
          const f16x8 bf = *(const f16x8*)((const char*)&Bs[rr][0] + (boff ^ key));
          if (t < 4)
            acc2[n] = __builtin_amdgcn_mfma_f32_16x16x32_f16(ahi[2 * tl + kk], bf, acc2[n], 0, 0, 0);
          else if (t < 8)
            acc2[n] = __builtin_amdgcn_mfma_f32_16x16x32_f16(alo[2 * tl + kk], bf, acc2[n], 0, 0, 0);
          else
            acc[n] = __builtin_amdgcn_mfma_f32_16x16x32_f16(ahi[2 * tl + kk], bf, acc[n], 0, 0, 0);
        }
      }
    }
  }

#pragma unroll
  for (int n = 0; n < 8; ++n) {
    const int ncol = n0 + n * 16 + lj;
    const float bb = bias[ncol];
#pragma unroll
    for (int j = 0; j < 4; ++j) {
      const int tok = m0 + w * 16 + li * 4 + j;
      const float vv = acc[n][j] + acc2[n][j] * LO_INV + bb;
      if (WEXT) {
        const f16 hh = (f16)vv;
        CextOut[(size_t)tok * 512 + ncol] = hh;
        CextOut[(size_t)tok * 512 + 256 + ncol] = (f16)((vv - (float)hh) * LO_SCALE);
      } else {
        Cout[(size_t)tok * Ntot + ncol] = vv;
      }
    }
  }
}

extern "C" void kernel_launch(void* const* d_in, const int* in_sizes, int n_in,
                              void* d_out, int out_size, void* d_ws, size_t ws_size,
                              hipStream_t stream) {
  (void)in_sizes; (void)n_in; (void)out_size; (void)ws_size;
  const float* x     = (const float*)d_in[0];
  const float* W_in  = (const float*)d_in[1];
  const float* b_in  = (const float*)d_in[2];
  const float* W_out = (const float*)d_in[3];
  const float* b_out = (const float*)d_in[4];
  const float* cbs   = (const float*)d_in[5];

  float* out = (float*)d_out;                        // [BT, HIDDEN]
  float* q1  = out + (size_t)BT * HIDDEN;            // [BT, DDIM]
  float* q2  = q1 + (size_t)BT * DDIM;               // [BT, DDIM]
  float* com = q2 + (size_t)BT * DDIM;               // [1]

  f16*   rext      = (f16*)d_ws;                          // [BT][512]   32 MB
  float* qsum      = (float*)(rext + (size_t)BT * 512);   // [BT][256]   32 MB
  f16*   cbext     = (f16*)(qsum + (size_t)BT * DDIM);    // [8192][512]  8 MB
  f16*   W_inext   = cbext + (size_t)NQUANT * KCODE * 512; // [256][1024] 512 KB
  f16*   W_outext  = W_inext + (size_t)DDIM * 1024;        // [512][512]  512 KB
  float* cnorm     = (float*)(W_outext + (size_t)HIDDEN * 512);  // [NQ*K]
  float* commitAcc = cnorm + NQUANT * KCODE;
  unsigned* bar    = (unsigned*)(commitAcc + 1);

  cnorm_kernel<<<NQUANT * KCODE, 256, 0, stream>>>(cbs, cnorm);
  cbext_conv<<<NQUANT * KCODE, 256, 0, stream>>>(cbs, cbext);
  bext_conv<<<(DDIM * HIDDEN + 255) / 256, 256, 0, stream>>>(W_in, W_inext, DDIM, HIDDEN);
  bext_conv<<<(HIDDEN * DDIM + 255) / 256, 256, 0, stream>>>(W_out, W_outext, HIDDEN, DDIM);
  proj3<HIDDEN, true><<<dim3(BT / 128, DDIM / 128), 512, 0, stream>>>(
      x, W_inext, b_in, nullptr, rext, DDIM);
  zero2<<<1, 1, 0, stream>>>(commitAcc, bar);
  rvq_fused6<<<BT / 128, 512, 0, stream>>>(rext, cbext, cbs, cnorm,
                                           qsum, q1, q2, commitAcc, bar);
  proj3<DDIM, false><<<dim3(BT / 128, HIDDEN / 128), 512, 0, stream>>>(
      qsum, W_outext, b_out, out, nullptr, HIDDEN);
  finalize_com<<<1, 1, 0, stream>>>(commitAcc, com);
}